// Round 2
// baseline (2997.747 us; speedup 1.0000x reference)
//
#include <hip/hip_runtime.h>
#include <hip/hip_bf16.h>

// Problem constants
#define BB 4
#define LL 512
#define DD 1024
#define ND 512
#define ED 64
#define HH 16
#define MLPD 2048
#define DH 64
#define BL (BB*LL)          // 2048 rows
#define MODSTRIDE (6*DD)    // 6144

// ---------------------------------------------------------------------------
// LN with affine (for s): out = (x-mean)*rstd * w + b, per row of C elems
// ---------------------------------------------------------------------------
__global__ __launch_bounds__(256) void ln_affine_kernel(
    const float* __restrict__ in, const float* __restrict__ w,
    const float* __restrict__ b, float* __restrict__ out, int C)
{
    int row = blockIdx.x;
    const float* x = in + (size_t)row * C;
    float* y = out + (size_t)row * C;
    __shared__ float red[256];
    float s = 0.f;
    for (int c = threadIdx.x; c < C; c += 256) s += x[c];
    red[threadIdx.x] = s; __syncthreads();
    for (int st = 128; st > 0; st >>= 1) {
        if (threadIdx.x < st) red[threadIdx.x] += red[threadIdx.x + st];
        __syncthreads();
    }
    float mean = red[0] / C;
    __syncthreads();
    float v = 0.f;
    for (int c = threadIdx.x; c < C; c += 256) { float d = x[c] - mean; v += d * d; }
    red[threadIdx.x] = v; __syncthreads();
    for (int st = 128; st > 0; st >>= 1) {
        if (threadIdx.x < st) red[threadIdx.x] += red[threadIdx.x + st];
        __syncthreads();
    }
    float rstd = rsqrtf(red[0] / C + 1e-5f);
    for (int c = threadIdx.x; c < C; c += 256)
        y[c] = (x[c] - mean) * rstd * w[c] + b[c];
}

// ---------------------------------------------------------------------------
// modLN (for h): out = LN(x)*(1+scale)+shift ; scale/shift from mod buffer
// C = 1024 fixed, mod stride 6144
// ---------------------------------------------------------------------------
__global__ __launch_bounds__(256) void modln_kernel(
    const float* __restrict__ in, const float* __restrict__ mod,
    int shift_base, int scale_base, float* __restrict__ out)
{
    int row = blockIdx.x;
    const float* x = in + (size_t)row * DD;
    const float* mrow = mod + (size_t)row * MODSTRIDE;
    float* y = out + (size_t)row * DD;
    __shared__ float red[256];
    float s = 0.f;
    for (int c = threadIdx.x; c < DD; c += 256) s += x[c];
    red[threadIdx.x] = s; __syncthreads();
    for (int st = 128; st > 0; st >>= 1) {
        if (threadIdx.x < st) red[threadIdx.x] += red[threadIdx.x + st];
        __syncthreads();
    }
    float mean = red[0] / DD;
    __syncthreads();
    float v = 0.f;
    for (int c = threadIdx.x; c < DD; c += 256) { float d = x[c] - mean; v += d * d; }
    red[threadIdx.x] = v; __syncthreads();
    for (int st = 128; st > 0; st >>= 1) {
        if (threadIdx.x < st) red[threadIdx.x] += red[threadIdx.x + st];
        __syncthreads();
    }
    float rstd = rsqrtf(red[0] / DD + 1e-5f);
    for (int c = threadIdx.x; c < DD; c += 256) {
        float sc = mrow[scale_base + c];
        float sh = mrow[shift_base + c];
        y[c] = (x[c] - mean) * rstd * (1.f + sc) + sh;
    }
}

// ---------------------------------------------------------------------------
// Edge bias: per row (b,i,j): LN over 64 elems, then 16 dots with edge_w rows
// One wave per row. bias[b,h,i,j]
// ---------------------------------------------------------------------------
__global__ __launch_bounds__(256) void edge_bias_kernel(
    const float* __restrict__ p, const float* __restrict__ elw,
    const float* __restrict__ elb, const float* __restrict__ ew,
    const float* __restrict__ eb, float* __restrict__ bias)
{
    int wave = blockIdx.x * 4 + (threadIdx.x >> 6);
    int lane = threadIdx.x & 63;
    // wave = b*262144 + i*512 + j
    int j = wave & 511;
    int i = (wave >> 9) & 511;
    int b = wave >> 18;
    float v = p[(size_t)wave * 64 + lane];
    float s = v;
    #pragma unroll
    for (int m = 32; m >= 1; m >>= 1) s += __shfl_xor(s, m, 64);
    float mean = s * (1.f / 64.f);
    float d = v - mean;
    float q = d * d;
    #pragma unroll
    for (int m = 32; m >= 1; m >>= 1) q += __shfl_xor(q, m, 64);
    float rstd = rsqrtf(q * (1.f / 64.f) + 1e-5f);
    float pb = d * rstd * elw[lane] + elb[lane];
    float myout = 0.f;
    #pragma unroll
    for (int hh = 0; hh < 16; ++hh) {
        float t = pb * ew[hh * 64 + lane];
        #pragma unroll
        for (int m = 32; m >= 1; m >>= 1) t += __shfl_xor(t, m, 64);
        if (lane == hh) myout = t + eb[hh];
    }
    if (lane < 16)
        bias[((((size_t)b * 16 + lane) * 512) + i) * 512 + j] = myout;
}

// ---------------------------------------------------------------------------
// Tiled SGEMM: C[m][n] = epi(sum_k A[m][k]*W[n][k] + bias[n])
// 64x64 tile, 256 threads, 4x4 per thread, KB=16.
// EPI: 0 = none, 1 = silu, 2 = res + x*gate
// Assumes M%64==0, N%64==0, K%16==0 (true for all our shapes)
// ---------------------------------------------------------------------------
template<int EPI>
__global__ __launch_bounds__(256) void gemm_kernel(
    const float* __restrict__ A, const float* __restrict__ W,
    const float* __restrict__ bias, float* __restrict__ C,
    int M, int N, int K,
    const float* __restrict__ res, const float* __restrict__ gate, int gate_off)
{
    __shared__ float As[16][68];
    __shared__ float Ws[16][68];
    int m0 = blockIdx.y * 64, n0 = blockIdx.x * 64;
    int tid = threadIdx.x;
    int ty = tid >> 4, tx = tid & 15;
    float acc[4][4] = {};
    const float* Ap = A + (size_t)(m0 + (tid >> 2)) * K + (tid & 3) * 4;
    const float* Wp = W + (size_t)(n0 + (tid >> 2)) * K + (tid & 3) * 4;
    int mr = tid >> 2, kc = (tid & 3) * 4;

    for (int k0 = 0; k0 < K; k0 += 16) {
        float4 av = *(const float4*)(Ap + k0);
        float4 wv = *(const float4*)(Wp + k0);
        __syncthreads();
        As[kc + 0][mr] = av.x; As[kc + 1][mr] = av.y;
        As[kc + 2][mr] = av.z; As[kc + 3][mr] = av.w;
        Ws[kc + 0][mr] = wv.x; Ws[kc + 1][mr] = wv.y;
        Ws[kc + 2][mr] = wv.z; Ws[kc + 3][mr] = wv.w;
        __syncthreads();
        #pragma unroll
        for (int kk = 0; kk < 16; ++kk) {
            float4 a4 = *(const float4*)&As[kk][ty * 4];
            float4 b4 = *(const float4*)&Ws[kk][tx * 4];
            float a_[4] = {a4.x, a4.y, a4.z, a4.w};
            float b_[4] = {b4.x, b4.y, b4.z, b4.w};
            #pragma unroll
            for (int i = 0; i < 4; ++i)
                #pragma unroll
                for (int jj = 0; jj < 4; ++jj)
                    acc[i][jj] += a_[i] * b_[jj];
        }
    }

    #pragma unroll
    for (int i = 0; i < 4; ++i) {
        int m = m0 + ty * 4 + i;
        #pragma unroll
        for (int jj = 0; jj < 4; ++jj) {
            int n = n0 + tx * 4 + jj;
            float x = acc[i][jj] + bias[n];
            if (EPI == 1) x = x / (1.f + __expf(-x));
            if (EPI == 2) x = res[(size_t)m * N + n] +
                              x * gate[(size_t)m * MODSTRIDE + gate_off + n];
            C[(size_t)m * N + n] = x;
        }
    }
}

// ---------------------------------------------------------------------------
// Permute qkv [B,L,3,H,DH] (flat [BL,3072]) -> q/k/v [B,H,L,DH]
// ---------------------------------------------------------------------------
__global__ __launch_bounds__(256) void qkv_permute_kernel(
    const float* __restrict__ qkv, float* __restrict__ q,
    float* __restrict__ k, float* __restrict__ v)
{
    int idx = blockIdx.x * 256 + threadIdx.x;  // over B*H*L*64 = 2097152
    if (idx >= BB * HH * LL * DH) return;
    int d = idx & 63;
    int i = (idx >> 6) & 511;
    int h = (idx >> 15) & 15;
    int b = idx >> 19;
    size_t src = ((size_t)(b * LL + i)) * (3 * DD) + h * 64 + d;
    q[idx] = qkv[src];
    k[idx] = qkv[src + DD];
    v[idx] = qkv[src + 2 * DD];
}

// ---------------------------------------------------------------------------
// Attention: per (b,h,16-row i-tile): scores + bias, softmax, PV
// ---------------------------------------------------------------------------
__global__ __launch_bounds__(256) void attn_kernel(
    const float* __restrict__ Q, const float* __restrict__ K,
    const float* __restrict__ V, const float* __restrict__ ebias,
    float* __restrict__ obuf)
{
    const int TI = 16;
    int i0 = blockIdx.x * TI;
    int h = blockIdx.y;
    int b = blockIdx.z;
    int bh = b * HH + h;
    __shared__ float q_s[16][64];
    __shared__ float s_s[16][512];
    const float* Qb = Q + (size_t)bh * LL * DH;
    const float* Kb = K + (size_t)bh * LL * DH;
    const float* Vb = V + (size_t)bh * LL * DH;
    const float* biasb = ebias + (size_t)bh * LL * LL + (size_t)i0 * LL;

    for (int idx = threadIdx.x; idx < 16 * 64; idx += 256)
        q_s[idx >> 6][idx & 63] = Qb[(size_t)(i0 + (idx >> 6)) * 64 + (idx & 63)];
    __syncthreads();

    // scores
    for (int idx = threadIdx.x; idx < 16 * 512; idx += 256) {
        int ii = idx >> 9, j = idx & 511;
        const float4* kr = (const float4*)(Kb + (size_t)j * 64);
        const float4* qr = (const float4*)q_s[ii];
        float acc = 0.f;
        #pragma unroll
        for (int t = 0; t < 16; ++t) {
            float4 kv = kr[t], qv = qr[t];
            acc += qv.x * kv.x + qv.y * kv.y + qv.z * kv.z + qv.w * kv.w;
        }
        s_s[ii][j] = acc * 0.125f + biasb[ii * 512 + j];
    }
    __syncthreads();

    // softmax: group of 16 threads per row, strided j = r + t*16
    {
        int ii = threadIdx.x >> 4, r = threadIdx.x & 15;
        float mx = -1e30f;
        #pragma unroll 8
        for (int t = 0; t < 32; ++t) mx = fmaxf(mx, s_s[ii][r + t * 16]);
        #pragma unroll
        for (int m = 8; m >= 1; m >>= 1) mx = fmaxf(mx, __shfl_xor(mx, m, 16));
        float sum = 0.f;
        #pragma unroll 8
        for (int t = 0; t < 32; ++t) {
            float e = __expf(s_s[ii][r + t * 16] - mx);
            s_s[ii][r + t * 16] = e;
            sum += e;
        }
        #pragma unroll
        for (int m = 8; m >= 1; m >>= 1) sum += __shfl_xor(sum, m, 16);
        float inv = 1.f / sum;
        #pragma unroll 8
        for (int t = 0; t < 32; ++t) s_s[ii][r + t * 16] *= inv;
    }
    __syncthreads();

    // o = attn @ V
    int d = threadIdx.x & 63;
    int w = threadIdx.x >> 6;
    for (int pass = 0; pass < 4; ++pass) {
        int ii = pass * 4 + w;
        const float* sp = s_s[ii];
        const float* vp = Vb + d;
        float acc = 0.f;
        #pragma unroll 4
        for (int j = 0; j < 512; ++j) acc += sp[j] * vp[(size_t)j * 64];
        obuf[((size_t)b * LL + i0 + ii) * DD + h * 64 + d] = acc;
    }
}

// ---------------------------------------------------------------------------
// Launch
// ---------------------------------------------------------------------------
extern "C" void kernel_launch(void* const* d_in, const int* in_sizes, int n_in,
                              void* d_out, int out_size, void* d_ws, size_t ws_size,
                              hipStream_t stream)
{
    const float* h_in      = (const float*)d_in[0];
    const float* s_in      = (const float*)d_in[1];
    const float* p_in      = (const float*)d_in[2];
    const float* adaln_ln_w = (const float*)d_in[3];
    const float* adaln_ln_b = (const float*)d_in[4];
    const float* adaln_w1  = (const float*)d_in[5];
    const float* adaln_b1  = (const float*)d_in[6];
    const float* adaln_w2  = (const float*)d_in[7];
    const float* adaln_b2  = (const float*)d_in[8];
    const float* edge_ln_w = (const float*)d_in[9];
    const float* edge_ln_b = (const float*)d_in[10];
    const float* edge_w    = (const float*)d_in[11];
    const float* edge_b    = (const float*)d_in[12];
    const float* in_w      = (const float*)d_in[13];
    const float* in_b      = (const float*)d_in[14];
    const float* out_w     = (const float*)d_in[15];
    const float* out_b     = (const float*)d_in[16];
    const float* mlp_w1    = (const float*)d_in[17];
    const float* mlp_b1    = (const float*)d_in[18];
    const float* mlp_w2    = (const float*)d_in[19];
    const float* mlp_b2    = (const float*)d_in[20];
    float* out = (float*)d_out;

    char* ws = (char*)d_ws;
    // Workspace layout (bytes)
    float* mod   = (float*)(ws + 0);            // 2048*6144*4  = 50331648
    float* eb    = (float*)(ws + 50331648ULL);  // 4*16*512*512*4 = 67108864
    float* qp    = (float*)(ws + 117440512ULL); // 8388608
    float* kp    = (float*)(ws + 125829120ULL); // 8388608
    float* vp    = (float*)(ws + 134217728ULL); // 8388608
    float* h2    = (float*)(ws + 142606336ULL); // 8388608
    char*  S     = ws + 150994944ULL;           // scratch, 33554432
    float* xs    = (float*)(S);                 // 4 MB   [2048,512]
    float* y1    = (float*)(S + 4194304ULL);    // 4 MB   [2048,512]
    float* xmsa  = (float*)(S);                 // 8 MB   [2048,1024]
    float* qkv   = (float*)(S + 8388608ULL);    // 25 MB  [2048,3072]
    float* obuf  = (float*)(S);                 // 8 MB   [2048,1024]
    float* x2    = (float*)(S);                 // 8 MB   [2048,1024]
    float* mid   = (float*)(S + 8388608ULL);    // 16 MB  [2048,2048]

    // 1. xs = LN(s)*w+b
    ln_affine_kernel<<<BL, 256, 0, stream>>>(s_in, adaln_ln_w, adaln_ln_b, xs, ND);
    // 2. y1 = silu(xs @ w1.T + b1)
    gemm_kernel<1><<<dim3(ND / 64, BL / 64), 256, 0, stream>>>(
        xs, adaln_w1, adaln_b1, y1, BL, ND, ND, nullptr, nullptr, 0);
    // 3. mod = y1 @ w2.T + b2
    gemm_kernel<0><<<dim3(6 * DD / 64, BL / 64), 256, 0, stream>>>(
        y1, adaln_w2, adaln_b2, mod, BL, 6 * DD, ND, nullptr, nullptr, 0);
    // 4. edge bias
    edge_bias_kernel<<<BB * LL * LL / 4, 256, 0, stream>>>(
        p_in, edge_ln_w, edge_ln_b, edge_w, edge_b, eb);
    // 5. xmsa = LN(h)*(1+scale_msa)+shift_msa
    modln_kernel<<<BL, 256, 0, stream>>>(h_in, mod, 0, DD, xmsa);
    // 6. qkv = xmsa @ in_w.T + in_b
    gemm_kernel<0><<<dim3(3 * DD / 64, BL / 64), 256, 0, stream>>>(
        xmsa, in_w, in_b, qkv, BL, 3 * DD, DD, nullptr, nullptr, 0);
    // 7. permute to [B,H,L,DH]
    qkv_permute_kernel<<<BB * HH * LL * DH / 256, 256, 0, stream>>>(qkv, qp, kp, vp);
    // 8. attention
    attn_kernel<<<dim3(LL / 16, HH, BB), 256, 0, stream>>>(qp, kp, vp, eb, obuf);
    // 9. h2 = h + (obuf @ out_w.T + out_b) * gate_msa
    gemm_kernel<2><<<dim3(DD / 64, BL / 64), 256, 0, stream>>>(
        obuf, out_w, out_b, h2, BL, DD, DD, h_in, mod, 2 * DD);
    // 10. x2 = LN(h2)*(1+scale_mlp)+shift_mlp
    modln_kernel<<<BL, 256, 0, stream>>>(h2, mod, 3 * DD, 4 * DD, x2);
    // 11. mid = silu(x2 @ mlp_w1.T + mlp_b1)
    gemm_kernel<1><<<dim3(MLPD / 64, BL / 64), 256, 0, stream>>>(
        x2, mlp_w1, mlp_b1, mid, BL, MLPD, DD, nullptr, nullptr, 0);
    // 12. out = h2 + (mid @ mlp_w2.T + mlp_b2) * gate_mlp
    gemm_kernel<2><<<dim3(DD / 64, BL / 64), 256, 0, stream>>>(
        mid, mlp_w2, mlp_b2, out, BL, DD, MLPD, h2, mod, 5 * DD);
}

// Round 4
// 1328.943 us; speedup vs baseline: 2.2557x; 2.2557x over previous
//
#include <hip/hip_runtime.h>
#include <hip/hip_bf16.h>

// Problem constants
#define BB 4
#define LL 512
#define DD 1024
#define ND 512
#define ED 64
#define HH 16
#define MLPD 2048
#define DH 64
#define BL (BB*LL)          // 2048 rows
#define MODSTRIDE (6*DD)    // 6144

typedef __hip_bfloat16 bf16;
typedef __attribute__((ext_vector_type(8))) short short8;
typedef __attribute__((ext_vector_type(4))) float f32x4;

// ---------------------------------------------------------------------------
// async global->LDS, 16B per lane. lds base must be wave-uniform.
// ---------------------------------------------------------------------------
__device__ __forceinline__ void gload_lds16(const void* g, void* l) {
    __builtin_amdgcn_global_load_lds(
        (const __attribute__((address_space(1))) unsigned int*)g,
        (__attribute__((address_space(3))) unsigned int*)l, 16, 0, 0);
}

// ---------------------------------------------------------------------------
// f32 -> bf16 elementwise (weights). n divisible by 1024.
// ---------------------------------------------------------------------------
__global__ __launch_bounds__(256) void cvt_bf16_kernel(
    const float* __restrict__ in, bf16* __restrict__ o, int n)
{
    int i = (blockIdx.x * 256 + threadIdx.x) * 4;
    if (i >= n) return;
    float4 v = *(const float4*)(in + i);
    union { bf16 h[4]; ushort2 u2[2]; } pk;
    pk.h[0] = __float2bfloat16(v.x); pk.h[1] = __float2bfloat16(v.y);
    pk.h[2] = __float2bfloat16(v.z); pk.h[3] = __float2bfloat16(v.w);
    *(ushort2*)(o + i) = pk.u2[0];
    *(ushort2*)(o + i + 2) = pk.u2[1];
}

// ---------------------------------------------------------------------------
// LN with affine (for s): out(bf16) = (x-mean)*rstd * w + b
// ---------------------------------------------------------------------------
__global__ __launch_bounds__(256) void ln_affine_kernel(
    const float* __restrict__ in, const float* __restrict__ w,
    const float* __restrict__ b, bf16* __restrict__ out, int C)
{
    int row = blockIdx.x;
    const float* x = in + (size_t)row * C;
    bf16* y = out + (size_t)row * C;
    __shared__ float red[256];
    float s = 0.f;
    for (int c = threadIdx.x; c < C; c += 256) s += x[c];
    red[threadIdx.x] = s; __syncthreads();
    for (int st = 128; st > 0; st >>= 1) {
        if (threadIdx.x < st) red[threadIdx.x] += red[threadIdx.x + st];
        __syncthreads();
    }
    float mean = red[0] / C;
    __syncthreads();
    float v = 0.f;
    for (int c = threadIdx.x; c < C; c += 256) { float d = x[c] - mean; v += d * d; }
    red[threadIdx.x] = v; __syncthreads();
    for (int st = 128; st > 0; st >>= 1) {
        if (threadIdx.x < st) red[threadIdx.x] += red[threadIdx.x + st];
        __syncthreads();
    }
    float rstd = rsqrtf(red[0] / C + 1e-5f);
    for (int c = threadIdx.x; c < C; c += 256)
        y[c] = __float2bfloat16((x[c] - mean) * rstd * w[c] + b[c]);
}

// ---------------------------------------------------------------------------
// modLN (for h): out(bf16) = LN(x)*(1+scale)+shift from mod buffer
// ---------------------------------------------------------------------------
__global__ __launch_bounds__(256) void modln_kernel(
    const float* __restrict__ in, const float* __restrict__ mod,
    int shift_base, int scale_base, bf16* __restrict__ out)
{
    int row = blockIdx.x;
    const float* x = in + (size_t)row * DD;
    const float* mrow = mod + (size_t)row * MODSTRIDE;
    bf16* y = out + (size_t)row * DD;
    __shared__ float red[256];
    float s = 0.f;
    for (int c = threadIdx.x; c < DD; c += 256) s += x[c];
    red[threadIdx.x] = s; __syncthreads();
    for (int st = 128; st > 0; st >>= 1) {
        if (threadIdx.x < st) red[threadIdx.x] += red[threadIdx.x + st];
        __syncthreads();
    }
    float mean = red[0] / DD;
    __syncthreads();
    float v = 0.f;
    for (int c = threadIdx.x; c < DD; c += 256) { float d = x[c] - mean; v += d * d; }
    red[threadIdx.x] = v; __syncthreads();
    for (int st = 128; st > 0; st >>= 1) {
        if (threadIdx.x < st) red[threadIdx.x] += red[threadIdx.x + st];
        __syncthreads();
    }
    float rstd = rsqrtf(red[0] / DD + 1e-5f);
    for (int c = threadIdx.x; c < DD; c += 256) {
        float sc = mrow[scale_base + c];
        float sh = mrow[shift_base + c];
        y[c] = __float2bfloat16((x[c] - mean) * rstd * (1.f + sc) + sh);
    }
}

// ---------------------------------------------------------------------------
// Edge bias v2: one THREAD per (b,i,j) row. Wave stages 64 rows into LDS
// coalesced, each lane processes its own row entirely in registers.
// Zero cross-lane ops. Output bf16.
// ---------------------------------------------------------------------------
__global__ __launch_bounds__(64) void edge_bias_kernel(
    const float* __restrict__ p, const float* __restrict__ elw,
    const float* __restrict__ elb, const float* __restrict__ ew,
    const float* __restrict__ ebv, bf16* __restrict__ bias)
{
    __shared__ float rowbuf[64 * 68];
    const int l = threadIdx.x;
    const int rbase = blockIdx.x * 64;
    const float4* src = (const float4*)(p + (size_t)rbase * 64);
    #pragma unroll
    for (int it = 0; it < 16; ++it) {
        int q = it * 64 + l;          // quad index, coalesced 1KB/wave/iter
        float4 v = src[q];
        int r = q >> 4, c = (q & 15) * 4;
        *(float4*)&rowbuf[r * 68 + c] = v;
    }
    __syncthreads();
    float x[64];
    float sum = 0.f, sq = 0.f;
    #pragma unroll
    for (int it = 0; it < 16; ++it) {
        float4 v = *(const float4*)&rowbuf[l * 68 + it * 4];
        x[it * 4 + 0] = v.x; x[it * 4 + 1] = v.y;
        x[it * 4 + 2] = v.z; x[it * 4 + 3] = v.w;
        sum += v.x + v.y + v.z + v.w;
        sq += v.x * v.x + v.y * v.y + v.z * v.z + v.w * v.w;
    }
    float mean = sum * (1.f / 64.f);
    float var = sq * (1.f / 64.f) - mean * mean;
    float rstd = rsqrtf(var + 1e-5f);
    float acc[16];
    #pragma unroll
    for (int h = 0; h < 16; ++h) acc[h] = 0.f;
    #pragma unroll
    for (int e = 0; e < 64; ++e) {
        float pbv = (x[e] - mean) * rstd * elw[e] + elb[e];  // elw/elb: uniform -> s_load
        #pragma unroll
        for (int h = 0; h < 16; ++h) acc[h] += pbv * ew[h * 64 + e];
    }
    int j = (rbase & 511) + l;
    int i = (rbase >> 9) & 511;
    int b = rbase >> 18;
    size_t base = (((size_t)b * 16) * 512 + i) * 512 + j;
    #pragma unroll
    for (int h = 0; h < 16; ++h)
        bias[base + (size_t)h * 512 * 512] = __float2bfloat16(acc[h] + ebv[h]);
}

// ---------------------------------------------------------------------------
// bf16 MFMA GEMM (m97-style): C[m][n] = epi(sum_k A[m][k]*W[n][k] + bias[n])
// A:[M][K] bf16 row-major, W:[N][K] bf16 row-major (= B^T layout).
// 128x128 tile, BK=32, 4 waves (2x2), mfma_f32_16x16x32_bf16.
// EPI: 0 none, 1 silu, 2 res + x*gate. OBF: output bf16 (EPI 0/1 only).
// ---------------------------------------------------------------------------
template<int EPI, int OBF>
__global__ __launch_bounds__(256) void gemm_bf16_kernel(
    const bf16* __restrict__ A, const bf16* __restrict__ W,
    const float* __restrict__ bias, void* __restrict__ Cout,
    int M, int N, int K,
    const float* __restrict__ res, const float* __restrict__ gate, int gate_off)
{
    __shared__ __align__(16) short As[128 * 32];
    __shared__ __align__(16) short Bs[128 * 32];
    const int tid = threadIdx.x;
    const int wave = tid >> 6, lane = tid & 63;
    const int fr = lane & 15, fq = lane >> 4;
    const int m0 = blockIdx.y * 128, n0 = blockIdx.x * 128;
    const int wr = wave >> 1, wc = wave & 1;

    // staging geometry: thread covers LDS element offsets tid*8 + c*2048
    const int srow = tid >> 2;            // + c*64
    const int scol = (tid & 3) * 8;       // k element offset within BK
    short* lbaseA0 = As + wave * 512;
    short* lbaseA1 = As + wave * 512 + 2048;
    short* lbaseB0 = Bs + wave * 512;
    short* lbaseB1 = Bs + wave * 512 + 2048;

    f32x4 acc[4][4] = {};

    for (int k0 = 0; k0 < K; k0 += 32) {
        gload_lds16(A + (size_t)(m0 + srow) * K + k0 + scol, lbaseA0);
        gload_lds16(A + (size_t)(m0 + srow + 64) * K + k0 + scol, lbaseA1);
        gload_lds16(W + (size_t)(n0 + srow) * K + k0 + scol, lbaseB0);
        gload_lds16(W + (size_t)(n0 + srow + 64) * K + k0 + scol, lbaseB1);
        __syncthreads();   // drains vmcnt before barrier (compiler-inserted)
        short8 af[4], bf[4];
        #pragma unroll
        for (int mi = 0; mi < 4; ++mi)
            af[mi] = *(const short8*)&As[(wr * 64 + mi * 16 + fr) * 32 + fq * 8];
        #pragma unroll
        for (int ni = 0; ni < 4; ++ni)
            bf[ni] = *(const short8*)&Bs[(wc * 64 + ni * 16 + fr) * 32 + fq * 8];
        #pragma unroll
        for (int mi = 0; mi < 4; ++mi)
            #pragma unroll
            for (int ni = 0; ni < 4; ++ni)
                acc[mi][ni] = __builtin_amdgcn_mfma_f32_16x16x32_bf16(
                    af[mi], bf[ni], acc[mi][ni], 0, 0, 0);
        __syncthreads();   // all waves done reading LDS before next stage
    }

    #pragma unroll
    for (int mi = 0; mi < 4; ++mi) {
        #pragma unroll
        for (int ni = 0; ni < 4; ++ni) {
            int n = n0 + wc * 64 + ni * 16 + fr;
            #pragma unroll
            for (int q = 0; q < 4; ++q) {
                int m = m0 + wr * 64 + mi * 16 + fq * 4 + q;
                float xv = acc[mi][ni][q] + bias[n];
                if (EPI == 1) xv = xv / (1.f + __expf(-xv));
                if (EPI == 2) xv = res[(size_t)m * N + n] +
                                   xv * gate[(size_t)m * MODSTRIDE + gate_off + n];
                if (OBF) ((bf16*)Cout)[(size_t)m * N + n] = __float2bfloat16(xv);
                else     ((float*)Cout)[(size_t)m * N + n] = xv;
            }
        }
    }
}

// ---------------------------------------------------------------------------
// Permute qkv bf16 [BL, 3*D] -> q/k/v f32 [B,H,L,DH]
// ---------------------------------------------------------------------------
__global__ __launch_bounds__(256) void qkv_permute_kernel(
    const bf16* __restrict__ qkv, float* __restrict__ q,
    float* __restrict__ k, float* __restrict__ v)
{
    int idx = blockIdx.x * 256 + threadIdx.x;  // over B*H*L*64 = 2097152
    if (idx >= BB * HH * LL * DH) return;
    int d = idx & 63;
    int i = (idx >> 6) & 511;
    int h = (idx >> 15) & 15;
    int b = idx >> 19;
    size_t src = ((size_t)(b * LL + i)) * (3 * DD) + h * 64 + d;
    q[idx] = __bfloat162float(qkv[src]);
    k[idx] = __bfloat162float(qkv[src + DD]);
    v[idx] = __bfloat162float(qkv[src + 2 * DD]);
}

// ---------------------------------------------------------------------------
// Attention: per (b,h,16-row i-tile): scores + bias(bf16), softmax, PV.
// Output obuf in bf16 (feeds MFMA out-proj GEMM).
// ---------------------------------------------------------------------------
__global__ __launch_bounds__(256) void attn_kernel(
    const float* __restrict__ Q, const float* __restrict__ K,
    const float* __restrict__ V, const bf16* __restrict__ ebias,
    bf16* __restrict__ obuf)
{
    const int TI = 16;
    int i0 = blockIdx.x * TI;
    int h = blockIdx.y;
    int b = blockIdx.z;
    int bh = b * HH + h;
    __shared__ float q_s[16][64];
    __shared__ float s_s[16][512];
    const float* Qb = Q + (size_t)bh * LL * DH;
    const float* Kb = K + (size_t)bh * LL * DH;
    const float* Vb = V + (size_t)bh * LL * DH;
    const bf16* biasb = ebias + (size_t)bh * LL * LL + (size_t)i0 * LL;

    for (int idx = threadIdx.x; idx < 16 * 64; idx += 256)
        q_s[idx >> 6][idx & 63] = Qb[(size_t)(i0 + (idx >> 6)) * 64 + (idx & 63)];
    __syncthreads();

    for (int idx = threadIdx.x; idx < 16 * 512; idx += 256) {
        int ii = idx >> 9, j = idx & 511;
        const float4* kr = (const float4*)(Kb + (size_t)j * 64);
        const float4* qr = (const float4*)q_s[ii];
        float acc = 0.f;
        #pragma unroll
        for (int t = 0; t < 16; ++t) {
            float4 kv = kr[t], qv = qr[t];
            acc += qv.x * kv.x + qv.y * kv.y + qv.z * kv.z + qv.w * kv.w;
        }
        s_s[ii][j] = acc * 0.125f + __bfloat162float(biasb[ii * 512 + j]);
    }
    __syncthreads();

    {
        int ii = threadIdx.x >> 4, r = threadIdx.x & 15;
        float mx = -1e30f;
        #pragma unroll 8
        for (int t = 0; t < 32; ++t) mx = fmaxf(mx, s_s[ii][r + t * 16]);
        #pragma unroll
        for (int m = 8; m >= 1; m >>= 1) mx = fmaxf(mx, __shfl_xor(mx, m, 16));
        float sum = 0.f;
        #pragma unroll 8
        for (int t = 0; t < 32; ++t) {
            float e = __expf(s_s[ii][r + t * 16] - mx);
            s_s[ii][r + t * 16] = e;
            sum += e;
        }
        #pragma unroll
        for (int m = 8; m >= 1; m >>= 1) sum += __shfl_xor(sum, m, 16);
        float inv = 1.f / sum;
        #pragma unroll 8
        for (int t = 0; t < 32; ++t) s_s[ii][r + t * 16] *= inv;
    }
    __syncthreads();

    int d = threadIdx.x & 63;
    int w = threadIdx.x >> 6;
    for (int pass = 0; pass < 4; ++pass) {
        int ii = pass * 4 + w;
        const float* sp = s_s[ii];
        const float* vpp = Vb + d;
        float acc = 0.f;
        #pragma unroll 4
        for (int j = 0; j < 512; ++j) acc += sp[j] * vpp[(size_t)j * 64];
        obuf[((size_t)b * LL + i0 + ii) * DD + h * 64 + d] = __float2bfloat16(acc);
    }
}

// ---------------------------------------------------------------------------
// Launch
// ---------------------------------------------------------------------------
extern "C" void kernel_launch(void* const* d_in, const int* in_sizes, int n_in,
                              void* d_out, int out_size, void* d_ws, size_t ws_size,
                              hipStream_t stream)
{
    const float* h_in      = (const float*)d_in[0];
    const float* s_in      = (const float*)d_in[1];
    const float* p_in      = (const float*)d_in[2];
    const float* adaln_ln_w = (const float*)d_in[3];
    const float* adaln_ln_b = (const float*)d_in[4];
    const float* adaln_w1  = (const float*)d_in[5];
    const float* adaln_b1  = (const float*)d_in[6];
    const float* adaln_w2  = (const float*)d_in[7];
    const float* adaln_b2  = (const float*)d_in[8];
    const float* edge_ln_w = (const float*)d_in[9];
    const float* edge_ln_b = (const float*)d_in[10];
    const float* edge_w    = (const float*)d_in[11];
    const float* edge_b    = (const float*)d_in[12];
    const float* in_w      = (const float*)d_in[13];
    const float* in_b      = (const float*)d_in[14];
    const float* out_w     = (const float*)d_in[15];
    const float* out_b     = (const float*)d_in[16];
    const float* mlp_w1    = (const float*)d_in[17];
    const float* mlp_b1    = (const float*)d_in[18];
    const float* mlp_w2    = (const float*)d_in[19];
    const float* mlp_b2    = (const float*)d_in[20];
    float* out = (float*)d_out;

    char* ws = (char*)d_ws;
    // fixed buffers
    float* mod   = (float*)(ws + 0);             // f32 [2048,6144]  50331648
    bf16*  eb    = (bf16*)(ws + 50331648ULL);    // bf16 [4,16,512,512] 33554432
    float* qp    = (float*)(ws + 83886080ULL);   // 8388608
    float* kp    = (float*)(ws + 92274688ULL);   // 8388608
    float* vp    = (float*)(ws + 100663296ULL);  // 8388608
    float* h2    = (float*)(ws + 109051904ULL);  // 8388608
    bf16*  wb1   = (bf16*)(ws + 117440512ULL);   // 524288
    bf16*  wb2   = (bf16*)(ws + 117964800ULL);   // 6291456
    bf16*  win   = (bf16*)(ws + 124256256ULL);   // 6291456
    bf16*  wout  = (bf16*)(ws + 130547712ULL);   // 2097152
    bf16*  wm1   = (bf16*)(ws + 132644864ULL);   // 4194304
    bf16*  wm2   = (bf16*)(ws + 136839168ULL);   // 4194304
    char*  S     = ws + 141033472ULL;            // scratch region (~21 MB)
    bf16*  xs    = (bf16*)(S);                   // [2048,512]
    bf16*  y1    = (bf16*)(S + 2097152ULL);      // [2048,512]
    bf16*  xmsa  = (bf16*)(S + 4194304ULL);      // [2048,1024]
    bf16*  qkv   = (bf16*)(S + 8388608ULL);      // [2048,3072] 12.6MB
    bf16*  obuf  = (bf16*)(S);                   // [2048,1024]
    bf16*  x2    = (bf16*)(S);                   // [2048,1024]
    bf16*  mid   = (bf16*)(S + 8388608ULL);      // [2048,2048]

    // 0. convert weights to bf16
    cvt_bf16_kernel<<<256, 256, 0, stream>>>(adaln_w1, wb1, ND * ND);
    cvt_bf16_kernel<<<3072, 256, 0, stream>>>(adaln_w2, wb2, 6 * DD * ND);
    cvt_bf16_kernel<<<3072, 256, 0, stream>>>(in_w, win, 3 * DD * DD);
    cvt_bf16_kernel<<<1024, 256, 0, stream>>>(out_w, wout, DD * DD);
    cvt_bf16_kernel<<<2048, 256, 0, stream>>>(mlp_w1, wm1, MLPD * DD);
    cvt_bf16_kernel<<<2048, 256, 0, stream>>>(mlp_w2, wm2, DD * MLPD);

    // 1. xs = LN(s)*w+b  (bf16)
    ln_affine_kernel<<<BL, 256, 0, stream>>>(s_in, adaln_ln_w, adaln_ln_b, xs, ND);
    // 2. y1 = silu(xs @ w1.T + b1)  (bf16)
    gemm_bf16_kernel<1, 1><<<dim3(ND / 128, BL / 128), 256, 0, stream>>>(
        xs, wb1, adaln_b1, y1, BL, ND, ND, nullptr, nullptr, 0);
    // 3. mod = y1 @ w2.T + b2  (f32)
    gemm_bf16_kernel<0, 0><<<dim3(6 * DD / 128, BL / 128), 256, 0, stream>>>(
        y1, wb2, adaln_b2, mod, BL, 6 * DD, ND, nullptr, nullptr, 0);
    // 4. edge bias (bf16 out)
    edge_bias_kernel<<<BB * LL * LL / 64, 64, 0, stream>>>(
        p_in, edge_ln_w, edge_ln_b, edge_w, edge_b, eb);
    // 5. xmsa = LN(h)*(1+scale_msa)+shift_msa  (bf16)
    modln_kernel<<<BL, 256, 0, stream>>>(h_in, mod, 0, DD, xmsa);
    // 6. qkv = xmsa @ in_w.T + in_b  (bf16)
    gemm_bf16_kernel<0, 1><<<dim3(3 * DD / 128, BL / 128), 256, 0, stream>>>(
        xmsa, win, in_b, qkv, BL, 3 * DD, DD, nullptr, nullptr, 0);
    // 7. permute to f32 [B,H,L,DH]
    qkv_permute_kernel<<<BB * HH * LL * DH / 256, 256, 0, stream>>>(qkv, qp, kp, vp);
    // 8. attention (obuf bf16)
    attn_kernel<<<dim3(LL / 16, HH, BB), 256, 0, stream>>>(qp, kp, vp, eb, obuf);
    // 9. h2 = h + (obuf @ out_w.T + out_b) * gate_msa  (f32)
    gemm_bf16_kernel<2, 0><<<dim3(DD / 128, BL / 128), 256, 0, stream>>>(
        obuf, wout, out_b, h2, BL, DD, DD, h_in, mod, 2 * DD);
    // 10. x2 = LN(h2)*(1+scale_mlp)+shift_mlp  (bf16)
    modln_kernel<<<BL, 256, 0, stream>>>(h2, mod, 3 * DD, 4 * DD, x2);
    // 11. mid = silu(x2 @ mlp_w1.T + mlp_b1)  (bf16)
    gemm_bf16_kernel<1, 1><<<dim3(MLPD / 128, BL / 128), 256, 0, stream>>>(
        x2, wm1, mlp_b1, mid, BL, MLPD, DD, nullptr, nullptr, 0);
    // 12. out = h2 + (mid @ mlp_w2.T + mlp_b2) * gate_mlp  (f32)
    gemm_bf16_kernel<2, 0><<<dim3(DD / 128, BL / 128), 256, 0, stream>>>(
        mid, wm2, mlp_b2, out, BL, DD, MLPD, h2, mod, 5 * DD);
}